// Round 3
// baseline (2918.664 us; speedup 1.0000x reference)
//
#include <hip/hip_runtime.h>
#include <hip/hip_bf16.h>

#define H 64
#define PADW 88    // bf16 plane row stride (shorts): 176B, 2-way bank alias (free), 16B aligned
#define PADU 136   // bf16 plane row stride for K=128 (shorts): 272B, 2-way alias, 16B aligned
#define PADT 68    // f32 transpose-buffer row stride (floats): 272B, 2-way alias, 16B aligned

typedef __attribute__((ext_vector_type(8))) short short8;
typedef __attribute__((ext_vector_type(4))) float floatx4;

#define MFMA(a, b, c) __builtin_amdgcn_mfma_f32_16x16x32_bf16(a, b, c, 0, 0, 0)

__device__ __forceinline__ float bf2f(short s) {
  union { unsigned int u; float f; } v;
  v.u = ((unsigned int)(unsigned short)s) << 16;
  return v.f;
}
__device__ __forceinline__ short f2bf(float f) {
  union { float f; unsigned int u; } v; v.f = f;
  unsigned int r = v.u + 0x7fffu + ((v.u >> 16) & 1u);  // RNE
  return (short)(r >> 16);
}
__device__ __forceinline__ void split2(float v, short& hi, short& lo) {
  hi = f2bf(v);
  lo = f2bf(v - bf2f(hi));
}
// element idx of a float tensor that is either f32 or bf16
__device__ __forceinline__ float ldf(const void* p, long idx, bool isf32) {
  return isf32 ? ((const float*)p)[idx] : bf2f(((const short*)p)[idx]);
}

// dtype probe: bf16 N(0,1) data -> sane exponents everywhere; f32 data -> low
// halves have uniform-random exponent fields (~84% "insane").
__global__ void k_probe(const short* __restrict__ x, int* __restrict__ flag) {
  __shared__ int cnt;
  if (threadIdx.x == 0) cnt = 0;
  __syncthreads();
  short s = x[threadIdx.x];
  int e = (s >> 7) & 0xFF;
  int insane = (e != 0 && (e < 100 || e > 140)) ? 1 : 0;
  atomicAdd(&cnt, insane);
  __syncthreads();
  if (threadIdx.x == 0) *flag = (cnt > 64) ? 1 : 0;  // 1 = f32 inputs
}

// h0 = relu(x @ w_in + b_in) -> f32
__global__ void k_input(const void* __restrict__ x, const void* __restrict__ w,
                        const void* __restrict__ b, float* __restrict__ h,
                        const int* __restrict__ flag, int N) {
  bool isf32 = (*flag != 0);
  int idx = blockIdx.x * 256 + threadIdx.x;
  if (idx >= N * H) return;
  int v = idx >> 6, k = idx & 63;
  float acc = ldf(b, k, isf32);
#pragma unroll
  for (int d = 0; d < 3; ++d)
    acc += ldf(x, (long)v * 3 + d, isf32) * ldf(w, d * 64 + k, isf32);
  h[idx] = fmaxf(acc, 0.f);
}

// per-edge message MLP (split-bf16 MFMA) + scatter-add. 4 waves/block, 16 edges/wave.
// oW/oB: element offsets of this layer's weights/biases into the stacked tensors.
template <bool AF32>
__global__ __launch_bounds__(256) void k_msg(
    const float* __restrict__ h, const int* __restrict__ srcI, const int* __restrict__ dstI,
    const void* __restrict__ W1, const void* __restrict__ B1,
    const void* __restrict__ W2, const void* __restrict__ B2,
    long oW, long oB,
    void* __restrict__ aggv, const int* __restrict__ flag, int E) {
  __shared__ short w1hi[64 * PADW], w1lo[64 * PADW];
  __shared__ short w2hi[64 * PADW], w2lo[64 * PADW];
  __shared__ float b1s[64], b2s[64];
  __shared__ float tbuf[4][16 * PADT];

  bool isf32 = (*flag != 0);
  int tid = threadIdx.x;
  for (int idx = tid; idx < 4096; idx += 256) {
    int j = idx >> 6, k = idx & 63;  // W[j][k] -> plane[k][j]
    short hi, lo;
    split2(ldf(W1, oW + idx, isf32), hi, lo);
    w1hi[k * PADW + j] = hi; w1lo[k * PADW + j] = lo;
    split2(ldf(W2, oW + idx, isf32), hi, lo);
    w2hi[k * PADW + j] = hi; w2lo[k * PADW + j] = lo;
  }
  if (tid < 64) {
    b1s[tid] = ldf(B1, oB + tid, isf32);
    b2s[tid] = ldf(B2, oB + tid, isf32);
  }
  __syncthreads();

  const int wave = tid >> 6, lane = tid & 63;
  const int m = lane & 15, quad = lane >> 4;
  const int eBase = (blockIdx.x * 4 + wave) * 16;

  int e = eBase + m;
  int ec = e < E ? e : E - 1;
  int sv = srcI[ec];
  int dv = dstI[ec];

  // A fragment: A[m][k = half*32 + quad*8 + j], split hi/lo
  const float* hrow = h + (long)sv * H;
  float av[16];
  *(floatx4*)(av + 0)  = *(const floatx4*)(hrow + quad * 8);
  *(floatx4*)(av + 4)  = *(const floatx4*)(hrow + quad * 8 + 4);
  *(floatx4*)(av + 8)  = *(const floatx4*)(hrow + 32 + quad * 8);
  *(floatx4*)(av + 12) = *(const floatx4*)(hrow + 32 + quad * 8 + 4);
  short8 ahi0, alo0, ahi1, alo1;
#pragma unroll
  for (int j = 0; j < 8; ++j) {
    short hi, lo;
    split2(av[j], hi, lo);     ahi0[j] = hi; alo0[j] = lo;
    split2(av[8 + j], hi, lo); ahi1[j] = hi; alo1[j] = lo;
  }

  floatx4 acc[4];
#pragma unroll
  for (int t = 0; t < 4; ++t) acc[t] = (floatx4){0.f, 0.f, 0.f, 0.f};
#pragma unroll
  for (int t = 0; t < 4; ++t) {
    const short* whi = &w1hi[(t * 16 + m) * PADW + quad * 8];
    const short* wlo = &w1lo[(t * 16 + m) * PADW + quad * 8];
    acc[t] = MFMA(ahi0, *(const short8*)(whi), acc[t]);
    acc[t] = MFMA(ahi1, *(const short8*)(whi + 32), acc[t]);
    acc[t] = MFMA(alo0, *(const short8*)(whi), acc[t]);
    acc[t] = MFMA(alo1, *(const short8*)(whi + 32), acc[t]);
    acc[t] = MFMA(ahi0, *(const short8*)(wlo), acc[t]);
    acc[t] = MFMA(ahi1, *(const short8*)(wlo + 32), acc[t]);
  }

  // C/D layout (col=lane&15, row=quad*4+r) -> f32 standard layout in LDS
  float* tb = tbuf[wave];
#pragma unroll
  for (int t = 0; t < 4; ++t) {
    int col = t * 16 + m;
    float bb = b1s[col];
#pragma unroll
    for (int r = 0; r < 4; ++r)
      tb[(quad * 4 + r) * PADT + col] = fmaxf(acc[t][r] + bb, 0.f);
  }
  __syncthreads();

  *(floatx4*)(av + 0)  = *(const floatx4*)(&tb[m * PADT + quad * 8]);
  *(floatx4*)(av + 4)  = *(const floatx4*)(&tb[m * PADT + quad * 8 + 4]);
  *(floatx4*)(av + 8)  = *(const floatx4*)(&tb[m * PADT + 32 + quad * 8]);
  *(floatx4*)(av + 12) = *(const floatx4*)(&tb[m * PADT + 32 + quad * 8 + 4]);
#pragma unroll
  for (int j = 0; j < 8; ++j) {
    short hi, lo;
    split2(av[j], hi, lo);     ahi0[j] = hi; alo0[j] = lo;
    split2(av[8 + j], hi, lo); ahi1[j] = hi; alo1[j] = lo;
  }

  floatx4 mac[4];
#pragma unroll
  for (int t = 0; t < 4; ++t) mac[t] = (floatx4){0.f, 0.f, 0.f, 0.f};
#pragma unroll
  for (int t = 0; t < 4; ++t) {
    const short* whi = &w2hi[(t * 16 + m) * PADW + quad * 8];
    const short* wlo = &w2lo[(t * 16 + m) * PADW + quad * 8];
    mac[t] = MFMA(ahi0, *(const short8*)(whi), mac[t]);
    mac[t] = MFMA(ahi1, *(const short8*)(whi + 32), mac[t]);
    mac[t] = MFMA(alo0, *(const short8*)(whi), mac[t]);
    mac[t] = MFMA(alo1, *(const short8*)(whi + 32), mac[t]);
    mac[t] = MFMA(ahi0, *(const short8*)(wlo), mac[t]);
    mac[t] = MFMA(ahi1, *(const short8*)(wlo + 32), mac[t]);
  }

  float* aggF = (float*)aggv;
  short* aggS = (short*)aggv;
#pragma unroll
  for (int t = 0; t < 4; ++t) {
    int col = t * 16 + m;
    float bb = b2s[col];
#pragma unroll
    for (int r = 0; r < 4; ++r) {
      int row = quad * 4 + r;
      int er = eBase + row;
      int dr = __shfl(dv, row);
      float v = mac[t][r] + bb;
      if (AF32) {
        if (er < E) atomicAdd(&aggF[(long)dr * H + col], v);
      } else {
        float v2 = __shfl_down(v, 1);
        if (((m & 1) == 0) && er < E) {
          unsigned int pk = ((unsigned int)(unsigned short)f2bf(v2) << 16) |
                            (unsigned int)(unsigned short)f2bf(v);
          unsafeAtomicAdd((__hip_bfloat162*)&aggS[(long)dr * H + col],
                          *(__hip_bfloat162*)&pk);
        }
      }
    }
  }
}

// per-node update MLP + BN + residual relu (split-bf16 MFMA). In-place safe:
// every h element read by this block is written only by the same thread, after the read.
template <bool AF32>
__global__ __launch_bounds__(256) void k_upd(
    const float* __restrict__ h, const void* __restrict__ aggv,
    const void* __restrict__ W1, const void* __restrict__ B1,
    const void* __restrict__ W2, const void* __restrict__ B2,
    const void* __restrict__ G, const void* __restrict__ Bb,
    const void* __restrict__ Mm, const void* __restrict__ Vv,
    long oU, long oW, long oB,
    float* __restrict__ hout, const int* __restrict__ flag, int N) {
  __shared__ short w1hi[64 * PADU], w1lo[64 * PADU];
  __shared__ short w2hi[64 * PADW], w2lo[64 * PADW];
  __shared__ float b1s[64], b2s[64], scl[64], sft[64];
  __shared__ float tbuf[4][16 * PADT];

  bool isf32 = (*flag != 0);
  int tid = threadIdx.x;
  for (int idx = tid; idx < 8192; idx += 256) {
    int j = idx >> 6, k = idx & 63;  // W1[j(128)][k(64)]
    short hi, lo;
    split2(ldf(W1, oU + idx, isf32), hi, lo);
    w1hi[k * PADU + j] = hi; w1lo[k * PADU + j] = lo;
  }
  for (int idx = tid; idx < 4096; idx += 256) {
    int j = idx >> 6, k = idx & 63;
    short hi, lo;
    split2(ldf(W2, oW + idx, isf32), hi, lo);
    w2hi[k * PADW + j] = hi; w2lo[k * PADW + j] = lo;
  }
  if (tid < 64) {
    b1s[tid] = ldf(B1, oB + tid, isf32);
    b2s[tid] = ldf(B2, oB + tid, isf32);
    float s = ldf(G, oB + tid, isf32) * rsqrtf(ldf(Vv, oB + tid, isf32) + 1e-5f);
    scl[tid] = s;
    sft[tid] = ldf(Bb, oB + tid, isf32) - ldf(Mm, oB + tid, isf32) * s;
  }
  __syncthreads();

  const int wave = tid >> 6, lane = tid & 63;
  const int m = lane & 15, quad = lane >> 4;
  const int nBase = (blockIdx.x * 4 + wave) * 16;
  int node = nBase + m;
  int nc = node < N ? node : N - 1;

  float av[16];
  const float* hrow = h + (long)nc * H;
  *(floatx4*)(av + 0)  = *(const floatx4*)(hrow + quad * 8);
  *(floatx4*)(av + 4)  = *(const floatx4*)(hrow + quad * 8 + 4);
  *(floatx4*)(av + 8)  = *(const floatx4*)(hrow + 32 + quad * 8);
  *(floatx4*)(av + 12) = *(const floatx4*)(hrow + 32 + quad * 8 + 4);
  float gv[16];
  if (AF32) {
    const float* arow = (const float*)aggv + (long)nc * H;
    *(floatx4*)(gv + 0)  = *(const floatx4*)(arow + quad * 8);
    *(floatx4*)(gv + 4)  = *(const floatx4*)(arow + quad * 8 + 4);
    *(floatx4*)(gv + 8)  = *(const floatx4*)(arow + 32 + quad * 8);
    *(floatx4*)(gv + 12) = *(const floatx4*)(arow + 32 + quad * 8 + 4);
  } else {
    const short* arow = (const short*)aggv + (long)nc * H;
#pragma unroll
    for (int j = 0; j < 8; ++j) {
      gv[j] = bf2f(arow[quad * 8 + j]);
      gv[8 + j] = bf2f(arow[32 + quad * 8 + j]);
    }
  }
  short8 fhi[4], flo[4];
#pragma unroll
  for (int j = 0; j < 8; ++j) {
    short hi, lo;
    split2(av[j], hi, lo);      fhi[0][j] = hi; flo[0][j] = lo;
    split2(av[8 + j], hi, lo);  fhi[1][j] = hi; flo[1][j] = lo;
    split2(gv[j], hi, lo);      fhi[2][j] = hi; flo[2][j] = lo;
    split2(gv[8 + j], hi, lo);  fhi[3][j] = hi; flo[3][j] = lo;
  }

  floatx4 acc[4];
#pragma unroll
  for (int t = 0; t < 4; ++t) acc[t] = (floatx4){0.f, 0.f, 0.f, 0.f};
#pragma unroll
  for (int t = 0; t < 4; ++t) {
    const short* whi = &w1hi[(t * 16 + m) * PADU + quad * 8];
    const short* wlo = &w1lo[(t * 16 + m) * PADU + quad * 8];
#pragma unroll
    for (int c = 0; c < 4; ++c) {
      acc[t] = MFMA(fhi[c], *(const short8*)(whi + 32 * c), acc[t]);
      acc[t] = MFMA(flo[c], *(const short8*)(whi + 32 * c), acc[t]);
      acc[t] = MFMA(fhi[c], *(const short8*)(wlo + 32 * c), acc[t]);
    }
  }

  float* tb = tbuf[wave];
#pragma unroll
  for (int t = 0; t < 4; ++t) {
    int col = t * 16 + m;
    float bb = b1s[col];
#pragma unroll
    for (int r = 0; r < 4; ++r)
      tb[(quad * 4 + r) * PADT + col] = fmaxf(acc[t][r] + bb, 0.f);
  }
  __syncthreads();

  *(floatx4*)(av + 0)  = *(const floatx4*)(&tb[m * PADT + quad * 8]);
  *(floatx4*)(av + 4)  = *(const floatx4*)(&tb[m * PADT + quad * 8 + 4]);
  *(floatx4*)(av + 8)  = *(const floatx4*)(&tb[m * PADT + 32 + quad * 8]);
  *(floatx4*)(av + 12) = *(const floatx4*)(&tb[m * PADT + 32 + quad * 8 + 4]);
  short8 thi0, tlo0, thi1, tlo1;
#pragma unroll
  for (int j = 0; j < 8; ++j) {
    short hi, lo;
    split2(av[j], hi, lo);     thi0[j] = hi; tlo0[j] = lo;
    split2(av[8 + j], hi, lo); thi1[j] = hi; tlo1[j] = lo;
  }

  floatx4 mac[4];
#pragma unroll
  for (int t = 0; t < 4; ++t) mac[t] = (floatx4){0.f, 0.f, 0.f, 0.f};
#pragma unroll
  for (int t = 0; t < 4; ++t) {
    const short* whi = &w2hi[(t * 16 + m) * PADW + quad * 8];
    const short* wlo = &w2lo[(t * 16 + m) * PADW + quad * 8];
    mac[t] = MFMA(thi0, *(const short8*)(whi), mac[t]);
    mac[t] = MFMA(thi1, *(const short8*)(whi + 32), mac[t]);
    mac[t] = MFMA(tlo0, *(const short8*)(whi), mac[t]);
    mac[t] = MFMA(tlo1, *(const short8*)(whi + 32), mac[t]);
    mac[t] = MFMA(thi0, *(const short8*)(wlo), mac[t]);
    mac[t] = MFMA(thi1, *(const short8*)(wlo + 32), mac[t]);
  }

#pragma unroll
  for (int t = 0; t < 4; ++t) {
    int col = t * 16 + m;
    float bb = b2s[col], ss = scl[col], ff = sft[col];
#pragma unroll
    for (int r = 0; r < 4; ++r) {
      int nrow = nBase + quad * 4 + r;
      if (nrow < N) {
        float hv = (mac[t][r] + bb) * ss + ff;
        float ho = h[(long)nrow * H + col];
        hout[(long)nrow * H + col] = fmaxf(hv + ho, 0.f);
      }
    }
  }
}

// out = relu(h[:NQ] @ out_w1 + b1) @ out_w2 + b2 ; one thread per node, f32 compute
__global__ __launch_bounds__(256) void k_out(
    const float* __restrict__ h, const void* __restrict__ W1, const void* __restrict__ B1,
    const void* __restrict__ W2, const void* __restrict__ B2,
    void* __restrict__ out, const int* __restrict__ flag, int NQ) {
  __shared__ float w1s[64 * 32];
  __shared__ float b1sh[32], w2s[32];
  bool isf32 = (*flag != 0);
  int tid = threadIdx.x;
  for (int idx = tid; idx < 2048; idx += 256) w1s[idx] = ldf(W1, idx, isf32);
  if (tid < 32) { b1sh[tid] = ldf(B1, tid, isf32); w2s[tid] = ldf(W2, tid, isf32); }
  __syncthreads();
  int v = blockIdx.x * 256 + tid;
  if (v >= NQ) return;
  float hr[64];
  const float* hp = h + (long)v * H;
#pragma unroll
  for (int j = 0; j < 64; ++j) hr[j] = hp[j];
  float accum = ldf(B2, 0, isf32);
#pragma unroll 4
  for (int k = 0; k < 32; ++k) {
    float t = b1sh[k];
#pragma unroll
    for (int j = 0; j < 64; ++j) t += hr[j] * w1s[j * 32 + k];
    accum += fmaxf(t, 0.f) * w2s[k];
  }
  if (isf32) ((float*)out)[v] = accum;
  else ((short*)out)[v] = f2bf(accum);
}

extern "C" void kernel_launch(void* const* d_in, const int* in_sizes, int n_in,
                              void* d_out, int out_size, void* d_ws, size_t ws_size,
                              hipStream_t stream) {
  const void* x      = d_in[0];
  const int*  ei     = (const int*)d_in[1];
  const void* w_in   = d_in[3];
  const void* b_in   = d_in[4];
  const void* msg_w1 = d_in[5];
  const void* msg_b1 = d_in[6];
  const void* msg_w2 = d_in[7];
  const void* msg_b2 = d_in[8];
  const void* upd_w1 = d_in[9];
  const void* upd_b1 = d_in[10];
  const void* upd_w2 = d_in[11];
  const void* upd_b2 = d_in[12];
  const void* bn_g   = d_in[13];
  const void* bn_b   = d_in[14];
  const void* bn_m   = d_in[15];
  const void* bn_v   = d_in[16];
  const void* out_w1 = d_in[17];
  const void* out_b1 = d_in[18];
  const void* out_w2 = d_in[19];
  const void* out_b2 = d_in[20];

  const int N = in_sizes[0] / 3;
  const int E = in_sizes[1] / 2;
  const int L = in_sizes[5] / (H * H);

  int*   flag = (int*)d_ws;
  float* hA   = (float*)((char*)d_ws + 256);
  const size_t hBytes   = (size_t)N * H * sizeof(float);
  const size_t aggF32B  = (size_t)N * H * sizeof(float);
  const size_t aggBf16B = (size_t)N * H * sizeof(short);
  void* agg = (void*)((char*)hA + hBytes);
  const bool af32 = (ws_size >= 256 + hBytes + aggF32B);
  const size_t aggBytes = af32 ? aggF32B : aggBf16B;

  const int* srcI = ei;
  const int* dstI = ei + E;

  k_probe<<<1, 256, 0, stream>>>((const short*)x, flag);
  k_input<<<(N * H + 255) / 256, 256, 0, stream>>>(x, w_in, b_in, hA, flag, N);

  for (int i = 0; i < L; ++i) {
    long oW = (long)i * H * H;       // 4096 elements per layer
    long oU = (long)i * 2 * H * H;   // 8192 elements per layer
    long oB = (long)i * H;           // 64 elements per layer
    hipMemsetAsync(agg, 0, aggBytes, stream);
    if (af32) {
      k_msg<true><<<(E + 63) / 64, 256, 0, stream>>>(hA, srcI, dstI,
          msg_w1, msg_b1, msg_w2, msg_b2, oW, oB, agg, flag, E);
      k_upd<true><<<(N + 63) / 64, 256, 0, stream>>>(hA, agg,
          upd_w1, upd_b1, upd_w2, upd_b2, bn_g, bn_b, bn_m, bn_v,
          oU, oW, oB, hA, flag, N);
    } else {
      k_msg<false><<<(E + 63) / 64, 256, 0, stream>>>(hA, srcI, dstI,
          msg_w1, msg_b1, msg_w2, msg_b2, oW, oB, agg, flag, E);
      k_upd<false><<<(N + 63) / 64, 256, 0, stream>>>(hA, agg,
          upd_w1, upd_b1, upd_w2, upd_b2, bn_g, bn_b, bn_m, bn_v,
          oU, oW, oB, hA, flag, N);
    }
  }

  k_out<<<(out_size + 255) / 256, 256, 0, stream>>>(hA, out_w1, out_b1, out_w2, out_b2,
                                                    d_out, flag, out_size);
}